// Round 18
// baseline (479.449 us; speedup 1.0000x reference)
//
#include <hip/hip_runtime.h>
#include <hip/hip_fp16.h>
#include <cstddef>
#include <cstdint>

namespace {

constexpr int N  = 50000;   // nodes  (must fit u16 for edge packing)
constexpr int E  = 800000;  // edges
constexpr int DH = 64;      // hidden dim
constexpr int DO = 32;      // output dim
constexpr int NB = (N + 255) / 256;   // 196 scan blocks
constexpr int FB = (E + 255) / 256;   // 3125 fill blocks (merged kernel)
constexpr int GB = (N + 63) / 64;     // 782 gemm1 tiles  (merged kernel)
static_assert(N < 65536, "src packed as u16");
static_assert(NB <= 256, "single-tile block scan");

__device__ inline uint16_t f2bf(float f) {   // RTNE
    union { float f; uint32_t u; } c; c.f = f;
    uint32_t r = c.u + 0x7FFFu + ((c.u >> 16) & 1u);
    return (uint16_t)(r >> 16);
}
// unpack packed pair of bf16 (low = first in memory)
__device__ inline void bf2x(uint32_t p, float& a, float& b) {
    union { uint32_t u; float f; } c0, c1;
    c0.u = p << 16; c1.u = p & 0xFFFF0000u;
    a = c0.f; b = c1.f;
}

// ---------------------------------------------------------------------------
__global__ void k_zero(int* __restrict__ cnt) {
    int i = blockIdx.x * blockDim.x + threadIdx.x;
    if (i < N) cnt[i] = 0;
}

// in-degree histogram + CSR rank claim. 1 edge/thread, tiny kernel ->
// high occupancy (lesson R14: never fuse into a register-heavy body).
__global__ void k_count(const int* __restrict__ dst, int* __restrict__ cnt,
                        int* __restrict__ rank) {
    int e = blockIdx.x * blockDim.x + threadIdx.x;
    if (e < E) rank[e] = atomicAdd(&cnt[dst[e]], 1);
}

// ---------------------------------------------------------------------------
// scanA: per-block (256-wide) inclusive scan of cnt -> incl, block total -> bsum
__global__ void k_scanA(const int* __restrict__ cnt, int* __restrict__ incl,
                        int* __restrict__ bsum) {
    __shared__ int ts[256];
    const int t = threadIdx.x;
    const int i = blockIdx.x * 256 + t;
    const int v = (i < N) ? cnt[i] : 0;
    ts[t] = v;
    __syncthreads();
#pragma unroll
    for (int off = 1; off < 256; off <<= 1) {
        const int u = (t >= off) ? ts[t - off] : 0;
        __syncthreads();
        ts[t] += u;
        __syncthreads();
    }
    if (i < N) incl[i] = ts[t];
    if (t == 255) bsum[blockIdx.x] = ts[255];
}

// scanBC (merged): each block redundantly scans the 196-entry bsum in LDS
// (trivial), takes its own exclusive base, emits rowptr/dinv.
__global__ void k_scanBC(const int* __restrict__ cnt, const int* __restrict__ incl,
                         const int* __restrict__ bsum, int* __restrict__ rowptr,
                         float* __restrict__ dinv) {
    __shared__ int ts[256];
    const int t = threadIdx.x;
    ts[t] = (t < NB) ? bsum[t] : 0;
    __syncthreads();
#pragma unroll
    for (int off = 1; off < 256; off <<= 1) {
        const int u = (t >= off) ? ts[t - off] : 0;
        __syncthreads();
        ts[t] += u;
        __syncthreads();
    }
    const int base = (blockIdx.x == 0) ? 0 : ts[blockIdx.x - 1];
    const int i = blockIdx.x * 256 + t;
    if (i >= N) return;
    const int c    = cnt[i];
    const int excl = base + incl[i] - c;
    rowptr[i] = excl;
    dinv[i]   = rsqrtf((float)(c + 1));
    if (i == N - 1) rowptr[N] = excl + c;   // == E
}

// ---------------------------------------------------------------------------
// Merged: blocks [0,FB) = CSR fill (atomic-free, latency-bound);
// blocks [FB,FB+GB) = gemm1 h1 = X@W1 -> bf16 (LDS-tiled, compute-bound).
// Independent work. __launch_bounds__(256,4) caps VGPR at 128 so the fill
// blocks keep ~16 waves/CU (R14 lesson: unbounded merge gave VGPR=232, 8% occ).
__launch_bounds__(256, 4)
__global__ void k_fillg(const int* __restrict__ src, const int* __restrict__ dst,
                        const int* __restrict__ rank, const int* __restrict__ rowptr,
                        const float* __restrict__ dinv, uint32_t* __restrict__ epack,
                        const float* __restrict__ X, const float* __restrict__ W1,
                        uint16_t* __restrict__ h1) {
    __shared__ float Ws[64 * DH];   // 16 KB
    __shared__ float Xs[64 * 68];   // 17.4 KB (padded stride 68)

    if (blockIdx.x < FB) {          // ---- fill body (low VGPR, no LDS use)
        const int e = blockIdx.x * 256 + threadIdx.x;
        if (e < E) {
            const int s = src[e], d = dst[e];
            const int pos = rowptr[d] + rank[e];
            const float wn = dinv[s] * dinv[d];
            const uint16_t hb = __half_as_ushort(__float2half(wn));
            epack[pos] = (uint32_t)s | ((uint32_t)hb << 16);
        }
        return;
    }

    // ---- gemm1 body (64-row tile, thread tile 4x4, ascending-k summation)
    const int tid = threadIdx.x;
    const int rowBase = (blockIdx.x - FB) * 64;

#pragma unroll
    for (int i = 0; i < 4; ++i) {   // stage W1: 1024 f4, coalesced
        const int q = tid + i * 256;
        reinterpret_cast<float4*>(Ws)[q] = reinterpret_cast<const float4*>(W1)[q];
    }
#pragma unroll
    for (int i = 0; i < 4; ++i) {   // stage X tile, coalesced; clamp tail rows
        const int q   = tid + i * 256;
        const int row = q >> 4;
        const int kq  = q & 15;
        const int gr  = min(rowBase + row, N - 1);
        const float4 v = *reinterpret_cast<const float4*>(X + (size_t)gr * 64 + kq * 4);
        *reinterpret_cast<float4*>(&Xs[row * 68 + kq * 4]) = v;
    }
    __syncthreads();

    const int rg = tid >> 4;        // row group (4 rows)
    const int cg = tid & 15;        // col group (4 cols)
    float acc[4][4];
#pragma unroll
    for (int r = 0; r < 4; ++r)
#pragma unroll
        for (int c = 0; c < 4; ++c) acc[r][c] = 0.0f;

#pragma unroll
    for (int k4 = 0; k4 < 16; ++k4) {
        const int k = k4 * 4;
        float xr[4][4];
#pragma unroll
        for (int r = 0; r < 4; ++r) {
            const float4 v = *reinterpret_cast<const float4*>(&Xs[(rg * 4 + r) * 68 + k]);
            xr[r][0] = v.x; xr[r][1] = v.y; xr[r][2] = v.z; xr[r][3] = v.w;
        }
#pragma unroll
        for (int i = 0; i < 4; ++i) {
            const float4 v = *reinterpret_cast<const float4*>(&Ws[(k + i) * DH + cg * 4]);
            const float wv[4] = {v.x, v.y, v.z, v.w};
#pragma unroll
            for (int r = 0; r < 4; ++r)
#pragma unroll
                for (int c = 0; c < 4; ++c) acc[r][c] += xr[r][i] * wv[c];
        }
    }

#pragma unroll
    for (int r = 0; r < 4; ++r) {
        const int row = rowBase + rg * 4 + r;
        if (row < N) {
            uint2 o;
            o.x = (uint32_t)f2bf(acc[r][0]) | ((uint32_t)f2bf(acc[r][1]) << 16);
            o.y = (uint32_t)f2bf(acc[r][2]) | ((uint32_t)f2bf(acc[r][3]) << 16);
            *reinterpret_cast<uint2*>(&h1[(size_t)row * DH + cg * 4]) = o;
        }
    }
}

// ---------------------------------------------------------------------------
// gemm2: h2[N,32] = y1[N,64] @ W2[64,32] -> bf16. LDS-tiled, y1 read once.
__launch_bounds__(256)
__global__ void k_gemm2(const float* __restrict__ Y, const float* __restrict__ W2,
                        uint16_t* __restrict__ h2) {
    __shared__ float Ws[64 * DO];   // 8 KB
    __shared__ float Xs[64 * 68];   // 17.4 KB

    const int tid = threadIdx.x;
    const int rowBase = blockIdx.x * 64;

#pragma unroll
    for (int i = 0; i < 2; ++i) {   // stage W2: 512 f4
        const int q = tid + i * 256;
        reinterpret_cast<float4*>(Ws)[q] = reinterpret_cast<const float4*>(W2)[q];
    }
#pragma unroll
    for (int i = 0; i < 4; ++i) {   // stage y1 tile
        const int q   = tid + i * 256;
        const int row = q >> 4;
        const int kq  = q & 15;
        const int gr  = min(rowBase + row, N - 1);
        const float4 v = *reinterpret_cast<const float4*>(Y + (size_t)gr * 64 + kq * 4);
        *reinterpret_cast<float4*>(&Xs[row * 68 + kq * 4]) = v;
    }
    __syncthreads();

    const int rg = tid >> 4;        // row group (4 rows)
    const int cg = tid & 15;        // col group (2 cols)
    float acc[4][2];
#pragma unroll
    for (int r = 0; r < 4; ++r) { acc[r][0] = 0.0f; acc[r][1] = 0.0f; }

#pragma unroll
    for (int k4 = 0; k4 < 16; ++k4) {
        const int k = k4 * 4;
        float xr[4][4];
#pragma unroll
        for (int r = 0; r < 4; ++r) {
            const float4 v = *reinterpret_cast<const float4*>(&Xs[(rg * 4 + r) * 68 + k]);
            xr[r][0] = v.x; xr[r][1] = v.y; xr[r][2] = v.z; xr[r][3] = v.w;
        }
#pragma unroll
        for (int i = 0; i < 4; ++i) {
            const float2 v = *reinterpret_cast<const float2*>(&Ws[(k + i) * DO + cg * 2]);
#pragma unroll
            for (int r = 0; r < 4; ++r) {
                acc[r][0] += xr[r][i] * v.x;
                acc[r][1] += xr[r][i] * v.y;
            }
        }
    }

#pragma unroll
    for (int r = 0; r < 4; ++r) {
        const int row = rowBase + rg * 4 + r;
        if (row < N) {
            const uint32_t o = (uint32_t)f2bf(acc[r][0]) | ((uint32_t)f2bf(acc[r][1]) << 16);
            *reinterpret_cast<uint32_t*>(&h2[(size_t)row * DO + cg * 2]) = o;
        }
    }
}

// ---------------------------------------------------------------------------
// Layer-1 aggregation, unfused (lesson R16). One wave per node;
// 8 groups(g) x 8 lanes(sl); y1 f32 out.
__launch_bounds__(256)
__global__ void k_agg1(const int* __restrict__ rowptr, const uint32_t* __restrict__ epack,
                       const uint16_t* __restrict__ h1, const float* __restrict__ dinv,
                       const float* __restrict__ b1, float* __restrict__ y1) {
    const int gtid = blockIdx.x * 256 + threadIdx.x;
    const int n    = gtid >> 6;
    const int lane = threadIdx.x & 63;
    if (n >= N) return;
    const int g  = lane >> 3;   // edge slot 0..7
    const int sl = lane & 7;    // 16B feature slice
    const int beg = rowptr[n], end = rowptr[n + 1];

    float acc[8] = {0.f, 0.f, 0.f, 0.f, 0.f, 0.f, 0.f, 0.f};
    for (int j = beg; j < end; j += 8) {
        const int jj = j + g;
        int s = 0; float wn = 0.0f;
        if (jj < end) {
            const uint32_t w = epack[jj];
            s  = (int)(w & 0xFFFFu);
            wn = __half2float(__ushort_as_half((uint16_t)(w >> 16)));
        }
        const uint4 v = *reinterpret_cast<const uint4*>(h1 + (size_t)s * DH + sl * 8);
        float f0, f1;
        bf2x(v.x, f0, f1); acc[0] += wn * f0; acc[1] += wn * f1;
        bf2x(v.y, f0, f1); acc[2] += wn * f0; acc[3] += wn * f1;
        bf2x(v.z, f0, f1); acc[4] += wn * f0; acc[5] += wn * f1;
        bf2x(v.w, f0, f1); acc[6] += wn * f0; acc[7] += wn * f1;
    }
#pragma unroll
    for (int m = 8; m < 64; m <<= 1)        // sum over the 8 edge-groups
#pragma unroll
        for (int k = 0; k < 8; ++k) acc[k] += __shfl_xor(acc[k], m);

    if (g < 2) {   // 16 lanes write 16B each = full 256B y1 row
        const float di = dinv[n], d2 = di * di;
        const int fb = sl * 8 + g * 4;     // feature base of this lane's float4
        const uint2 sv = *reinterpret_cast<const uint2*>(h1 + (size_t)n * DH + fb);
        float s0, s1, s2, s3;
        bf2x(sv.x, s0, s1); bf2x(sv.y, s2, s3);
        const float4 bv = *reinterpret_cast<const float4*>(b1 + fb);
        float4 o;
        o.x = fmaxf(acc[g * 4 + 0] + s0 * d2 + bv.x, 0.f);
        o.y = fmaxf(acc[g * 4 + 1] + s1 * d2 + bv.y, 0.f);
        o.z = fmaxf(acc[g * 4 + 2] + s2 * d2 + bv.z, 0.f);
        o.w = fmaxf(acc[g * 4 + 3] + s3 * d2 + bv.w, 0.f);
        *reinterpret_cast<float4*>(y1 + (size_t)n * DH + fb) = o;
    }
}

// ---------------------------------------------------------------------------
// Layer-2 aggregation from bf16 h2. One wave per node; 16 groups x 4 lanes
// (row = 32 bf16 = 64B = 4 x uint4) -> 16 rows in flight per load instr.
__global__ void k_agg2(const int* __restrict__ rowptr, const uint32_t* __restrict__ epack,
                       const uint16_t* __restrict__ h2, const float* __restrict__ dinv,
                       const float* __restrict__ b2, float* __restrict__ out) {
    const int gtid = blockIdx.x * blockDim.x + threadIdx.x;
    const int n    = gtid >> 6;
    const int lane = gtid & 63;
    if (n >= N) return;
    const int g  = lane >> 2;   // edge slot 0..15
    const int sl = lane & 3;    // features sl*8 .. sl*8+7
    const int beg = rowptr[n], end = rowptr[n + 1];

    float acc[8] = {0.f, 0.f, 0.f, 0.f, 0.f, 0.f, 0.f, 0.f};
    for (int j = beg; j < end; j += 16) {
        const int jj = j + g;
        int s = 0; float wn = 0.0f;
        if (jj < end) {
            const uint32_t w = epack[jj];
            s  = (int)(w & 0xFFFFu);
            wn = __half2float(__ushort_as_half((uint16_t)(w >> 16)));
        }
        const uint4 v = *reinterpret_cast<const uint4*>(h2 + (size_t)s * DO + sl * 8);
        float f0, f1;
        bf2x(v.x, f0, f1); acc[0] += wn * f0; acc[1] += wn * f1;
        bf2x(v.y, f0, f1); acc[2] += wn * f0; acc[3] += wn * f1;
        bf2x(v.z, f0, f1); acc[4] += wn * f0; acc[5] += wn * f1;
        bf2x(v.w, f0, f1); acc[6] += wn * f0; acc[7] += wn * f1;
    }
#pragma unroll
    for (int m = 4; m < 64; m <<= 1)    // sum over the 16 edge-groups
#pragma unroll
        for (int k = 0; k < 8; ++k) acc[k] += __shfl_xor(acc[k], m);

    if (g < 2) {   // 8 lanes x float4 = full 128B f32 out row
        const float di = dinv[n], d2 = di * di;
        const int fb = sl * 8 + g * 4;
        const uint2 sv = *reinterpret_cast<const uint2*>(h2 + (size_t)n * DO + fb);
        float s0, s1, s2, s3;
        bf2x(sv.x, s0, s1); bf2x(sv.y, s2, s3);
        const float4 bv = *reinterpret_cast<const float4*>(b2 + fb);
        float4 o;
        o.x = acc[g * 4 + 0] + s0 * d2 + bv.x;
        o.y = acc[g * 4 + 1] + s1 * d2 + bv.y;
        o.z = acc[g * 4 + 2] + s2 * d2 + bv.z;
        o.w = acc[g * 4 + 3] + s3 * d2 + bv.w;
        *reinterpret_cast<float4*>(out + (size_t)n * DO + fb) = o;
    }
}

// 64B-align each ws sub-buffer (16B vector loads require it)
template <typename T>
T* alignp(char*& p, size_t count) {
    uintptr_t u = ((uintptr_t)p + 63) & ~(uintptr_t)63;
    p = (char*)(u + count * sizeof(T));
    return (T*)u;
}

}  // namespace

extern "C" void kernel_launch(void* const* d_in, const int* in_sizes, int n_in,
                              void* d_out, int out_size, void* d_ws, size_t ws_size,
                              hipStream_t stream) {
    const float* x   = (const float*)d_in[0];
    const int*   ei  = (const int*)d_in[1];   // [2,E] int32: row0=src, row1=dst
    const float* W1  = (const float*)d_in[2];
    const float* b1  = (const float*)d_in[3];
    const float* W2  = (const float*)d_in[4];
    const float* b2  = (const float*)d_in[5];
    float* out = (float*)d_out;

    const int* src = ei;
    const int* dst = ei + E;

    // workspace layout, each 64B-aligned; total ~30 MB
    char* p = (char*)d_ws;
    int*      cnt    = alignp<int>(p, N);
    int*      rowptr = alignp<int>(p, N + 1);
    int*      rank   = alignp<int>(p, E);
    float*    dinv   = alignp<float>(p, N);
    int*      incl   = alignp<int>(p, N);
    int*      bsum   = alignp<int>(p, NB);
    uint32_t* epack  = alignp<uint32_t>(p, E);
    uint16_t* h1     = alignp<uint16_t>(p, (size_t)N * DH);   // bf16
    float*    y1     = alignp<float>(p, (size_t)N * DH);      // f32
    uint16_t* h2     = alignp<uint16_t>(p, (size_t)N * DO);   // bf16

    // 1. zero histogram
    hipLaunchKernelGGL(k_zero, dim3((N + 255) / 256), dim3(256), 0, stream, cnt);
    // 2. in-degree histogram + rank claim (1 edge/thread, high occupancy)
    hipLaunchKernelGGL(k_count, dim3((E + 255) / 256), dim3(256), 0, stream,
                       dst, cnt, rank);
    // 3. scanA -> incl, bsum
    hipLaunchKernelGGL(k_scanA, dim3(NB), dim3(256), 0, stream, cnt, incl, bsum);
    // 4. scanBC (merged) -> rowptr, dinv
    hipLaunchKernelGGL(k_scanBC, dim3(NB), dim3(256), 0, stream,
                       cnt, incl, bsum, rowptr, dinv);
    // 5. merged: CSR fill (blocks [0,FB)) || gemm1 (blocks [FB,FB+GB))
    hipLaunchKernelGGL(k_fillg, dim3(FB + GB), dim3(256), 0, stream,
                       src, dst, rank, rowptr, dinv, epack, x, W1, h1);
    // 6. y1 = relu(aggregate(h1) + self + b1)   (one wave per node)
    hipLaunchKernelGGL(k_agg1, dim3((N * 64 + 255) / 256), dim3(256), 0, stream,
                       rowptr, epack, h1, dinv, b1, y1);
    // 7. gemm2: h2 = y1 @ W2 (bf16, LDS-tiled)
    hipLaunchKernelGGL(k_gemm2, dim3((N + 63) / 64), dim3(256), 0, stream, y1, W2, h2);
    // 8. out = aggregate(h2) + self + b2
    hipLaunchKernelGGL(k_agg2, dim3((N * 64 + 255) / 256), dim3(256), 0, stream,
                       rowptr, epack, h2, dinv, b2, out);
}

// Round 19
// 151.338 us; speedup vs baseline: 3.1681x; 3.1681x over previous
//
#include <hip/hip_runtime.h>
#include <hip/hip_fp16.h>
#include <cstddef>
#include <cstdint>

namespace {

constexpr int N  = 50000;   // nodes  (must fit u16 for edge packing)
constexpr int E  = 800000;  // edges
constexpr int DH = 64;      // hidden dim
constexpr int DO = 32;      // output dim
constexpr int NB = (N + 255) / 256;   // 196 scan blocks
static_assert(N < 65536, "src packed as u16");
static_assert(NB <= 256, "single-tile block scan");

__device__ inline uint16_t f2bf(float f) {   // RTNE
    union { float f; uint32_t u; } c; c.f = f;
    uint32_t r = c.u + 0x7FFFu + ((c.u >> 16) & 1u);
    return (uint16_t)(r >> 16);
}
// unpack packed pair of bf16 (low = first in memory)
__device__ inline void bf2x(uint32_t p, float& a, float& b) {
    union { uint32_t u; float f; } c0, c1;
    c0.u = p << 16; c1.u = p & 0xFFFF0000u;
    a = c0.f; b = c1.f;
}

// ---------------------------------------------------------------------------
__global__ void k_zero(int* __restrict__ cnt) {
    int i = blockIdx.x * blockDim.x + threadIdx.x;
    if (i < N) cnt[i] = 0;
}

// in-degree histogram + CSR rank claim. 1 edge/thread, tiny kernel ->
// high occupancy (lesson R14/R18: keep latency-bound atomics in their own
// minimal-VGPR kernel; merging with gemm either starves occupancy or spills).
__global__ void k_count(const int* __restrict__ dst, int* __restrict__ cnt,
                        int* __restrict__ rank) {
    int e = blockIdx.x * blockDim.x + threadIdx.x;
    if (e < E) rank[e] = atomicAdd(&cnt[dst[e]], 1);
}

// ---------------------------------------------------------------------------
// scanA: per-block (256-wide) inclusive scan of cnt -> incl, block total -> bsum
__global__ void k_scanA(const int* __restrict__ cnt, int* __restrict__ incl,
                        int* __restrict__ bsum) {
    __shared__ int ts[256];
    const int t = threadIdx.x;
    const int i = blockIdx.x * 256 + t;
    const int v = (i < N) ? cnt[i] : 0;
    ts[t] = v;
    __syncthreads();
#pragma unroll
    for (int off = 1; off < 256; off <<= 1) {
        const int u = (t >= off) ? ts[t - off] : 0;
        __syncthreads();
        ts[t] += u;
        __syncthreads();
    }
    if (i < N) incl[i] = ts[t];
    if (t == 255) bsum[blockIdx.x] = ts[255];
}

// scanBC (merged, proven R18): each block redundantly scans the 196-entry
// bsum in LDS, takes its own exclusive base, emits rowptr/dinv.
__global__ void k_scanBC(const int* __restrict__ cnt, const int* __restrict__ incl,
                         const int* __restrict__ bsum, int* __restrict__ rowptr,
                         float* __restrict__ dinv) {
    __shared__ int ts[256];
    const int t = threadIdx.x;
    ts[t] = (t < NB) ? bsum[t] : 0;
    __syncthreads();
#pragma unroll
    for (int off = 1; off < 256; off <<= 1) {
        const int u = (t >= off) ? ts[t - off] : 0;
        __syncthreads();
        ts[t] += u;
        __syncthreads();
    }
    const int base = (blockIdx.x == 0) ? 0 : ts[blockIdx.x - 1];
    const int i = blockIdx.x * 256 + t;
    if (i >= N) return;
    const int c    = cnt[i];
    const int excl = base + incl[i] - c;
    rowptr[i] = excl;
    dinv[i]   = rsqrtf((float)(c + 1));
    if (i == N - 1) rowptr[N] = excl + c;   // == E
}

// CSR fill, atomic-free: pos = rowptr[dst] + rank (unique by construction).
// Standalone (lesson R18: merging with gemm1 under launch_bounds spilled
// the gemm accumulators to scratch -> 974 MB of spill traffic).
__global__ void k_fill(const int* __restrict__ src, const int* __restrict__ dst,
                       const int* __restrict__ rank, const int* __restrict__ rowptr,
                       const float* __restrict__ dinv, uint32_t* __restrict__ epack) {
    int e = blockIdx.x * blockDim.x + threadIdx.x;
    if (e >= E) return;
    const int s = src[e], d = dst[e];
    const int pos = rowptr[d] + rank[e];
    const float wn = dinv[s] * dinv[d];
    const uint16_t hb = __half_as_ushort(__float2half(wn));
    epack[pos] = (uint32_t)s | ((uint32_t)hb << 16);
}

// ---------------------------------------------------------------------------
// gemm1: h1[N,64] = X[N,64] @ W1[64,64] -> bf16. LDS-tiled, X read once.
__launch_bounds__(256)
__global__ void k_gemm1(const float* __restrict__ X, const float* __restrict__ W1,
                        uint16_t* __restrict__ h1) {
    __shared__ float Ws[64 * DH];   // 16 KB
    __shared__ float Xs[64 * 68];   // 17.4 KB (padded stride 68)

    const int tid = threadIdx.x;
    const int rowBase = blockIdx.x * 64;

#pragma unroll
    for (int i = 0; i < 4; ++i) {   // stage W1: 1024 f4, coalesced
        const int q = tid + i * 256;
        reinterpret_cast<float4*>(Ws)[q] = reinterpret_cast<const float4*>(W1)[q];
    }
#pragma unroll
    for (int i = 0; i < 4; ++i) {   // stage X tile, coalesced; clamp tail rows
        const int q   = tid + i * 256;
        const int row = q >> 4;
        const int kq  = q & 15;
        const int gr  = min(rowBase + row, N - 1);
        const float4 v = *reinterpret_cast<const float4*>(X + (size_t)gr * 64 + kq * 4);
        *reinterpret_cast<float4*>(&Xs[row * 68 + kq * 4]) = v;
    }
    __syncthreads();

    const int rg = tid >> 4;        // row group (4 rows)
    const int cg = tid & 15;        // col group (4 cols)
    float acc[4][4];
#pragma unroll
    for (int r = 0; r < 4; ++r)
#pragma unroll
        for (int c = 0; c < 4; ++c) acc[r][c] = 0.0f;

#pragma unroll
    for (int k4 = 0; k4 < 16; ++k4) {
        const int k = k4 * 4;
        float xr[4][4];
#pragma unroll
        for (int r = 0; r < 4; ++r) {
            const float4 v = *reinterpret_cast<const float4*>(&Xs[(rg * 4 + r) * 68 + k]);
            xr[r][0] = v.x; xr[r][1] = v.y; xr[r][2] = v.z; xr[r][3] = v.w;
        }
#pragma unroll
        for (int i = 0; i < 4; ++i) {
            const float4 v = *reinterpret_cast<const float4*>(&Ws[(k + i) * DH + cg * 4]);
            const float wv[4] = {v.x, v.y, v.z, v.w};
#pragma unroll
            for (int r = 0; r < 4; ++r)
#pragma unroll
                for (int c = 0; c < 4; ++c) acc[r][c] += xr[r][i] * wv[c];
        }
    }

#pragma unroll
    for (int r = 0; r < 4; ++r) {
        const int row = rowBase + rg * 4 + r;
        if (row < N) {
            uint2 o;
            o.x = (uint32_t)f2bf(acc[r][0]) | ((uint32_t)f2bf(acc[r][1]) << 16);
            o.y = (uint32_t)f2bf(acc[r][2]) | ((uint32_t)f2bf(acc[r][3]) << 16);
            *reinterpret_cast<uint2*>(&h1[(size_t)row * DH + cg * 4]) = o;
        }
    }
}

// ---------------------------------------------------------------------------
// gemm2: h2[N,32] = y1[N,64] @ W2[64,32] -> bf16. LDS-tiled, y1 read once.
__launch_bounds__(256)
__global__ void k_gemm2(const float* __restrict__ Y, const float* __restrict__ W2,
                        uint16_t* __restrict__ h2) {
    __shared__ float Ws[64 * DO];   // 8 KB
    __shared__ float Xs[64 * 68];   // 17.4 KB

    const int tid = threadIdx.x;
    const int rowBase = blockIdx.x * 64;

#pragma unroll
    for (int i = 0; i < 2; ++i) {   // stage W2: 512 f4
        const int q = tid + i * 256;
        reinterpret_cast<float4*>(Ws)[q] = reinterpret_cast<const float4*>(W2)[q];
    }
#pragma unroll
    for (int i = 0; i < 4; ++i) {   // stage y1 tile
        const int q   = tid + i * 256;
        const int row = q >> 4;
        const int kq  = q & 15;
        const int gr  = min(rowBase + row, N - 1);
        const float4 v = *reinterpret_cast<const float4*>(Y + (size_t)gr * 64 + kq * 4);
        *reinterpret_cast<float4*>(&Xs[row * 68 + kq * 4]) = v;
    }
    __syncthreads();

    const int rg = tid >> 4;        // row group (4 rows)
    const int cg = tid & 15;        // col group (2 cols)
    float acc[4][2];
#pragma unroll
    for (int r = 0; r < 4; ++r) { acc[r][0] = 0.0f; acc[r][1] = 0.0f; }

#pragma unroll
    for (int k4 = 0; k4 < 16; ++k4) {
        const int k = k4 * 4;
        float xr[4][4];
#pragma unroll
        for (int r = 0; r < 4; ++r) {
            const float4 v = *reinterpret_cast<const float4*>(&Xs[(rg * 4 + r) * 68 + k]);
            xr[r][0] = v.x; xr[r][1] = v.y; xr[r][2] = v.z; xr[r][3] = v.w;
        }
#pragma unroll
        for (int i = 0; i < 4; ++i) {
            const float2 v = *reinterpret_cast<const float2*>(&Ws[(k + i) * DO + cg * 2]);
#pragma unroll
            for (int r = 0; r < 4; ++r) {
                acc[r][0] += xr[r][i] * v.x;
                acc[r][1] += xr[r][i] * v.y;
            }
        }
    }

#pragma unroll
    for (int r = 0; r < 4; ++r) {
        const int row = rowBase + rg * 4 + r;
        if (row < N) {
            const uint32_t o = (uint32_t)f2bf(acc[r][0]) | ((uint32_t)f2bf(acc[r][1]) << 16);
            *reinterpret_cast<uint32_t*>(&h2[(size_t)row * DO + cg * 2]) = o;
        }
    }
}

// ---------------------------------------------------------------------------
// Layer-1 aggregation, unfused (lesson R16). One wave per node;
// 8 groups(g) x 8 lanes(sl); y1 f32 out.
__launch_bounds__(256)
__global__ void k_agg1(const int* __restrict__ rowptr, const uint32_t* __restrict__ epack,
                       const uint16_t* __restrict__ h1, const float* __restrict__ dinv,
                       const float* __restrict__ b1, float* __restrict__ y1) {
    const int gtid = blockIdx.x * 256 + threadIdx.x;
    const int n    = gtid >> 6;
    const int lane = threadIdx.x & 63;
    if (n >= N) return;
    const int g  = lane >> 3;   // edge slot 0..7
    const int sl = lane & 7;    // 16B feature slice
    const int beg = rowptr[n], end = rowptr[n + 1];

    float acc[8] = {0.f, 0.f, 0.f, 0.f, 0.f, 0.f, 0.f, 0.f};
    for (int j = beg; j < end; j += 8) {
        const int jj = j + g;
        int s = 0; float wn = 0.0f;
        if (jj < end) {
            const uint32_t w = epack[jj];
            s  = (int)(w & 0xFFFFu);
            wn = __half2float(__ushort_as_half((uint16_t)(w >> 16)));
        }
        const uint4 v = *reinterpret_cast<const uint4*>(h1 + (size_t)s * DH + sl * 8);
        float f0, f1;
        bf2x(v.x, f0, f1); acc[0] += wn * f0; acc[1] += wn * f1;
        bf2x(v.y, f0, f1); acc[2] += wn * f0; acc[3] += wn * f1;
        bf2x(v.z, f0, f1); acc[4] += wn * f0; acc[5] += wn * f1;
        bf2x(v.w, f0, f1); acc[6] += wn * f0; acc[7] += wn * f1;
    }
#pragma unroll
    for (int m = 8; m < 64; m <<= 1)        // sum over the 8 edge-groups
#pragma unroll
        for (int k = 0; k < 8; ++k) acc[k] += __shfl_xor(acc[k], m);

    if (g < 2) {   // 16 lanes write 16B each = full 256B y1 row
        const float di = dinv[n], d2 = di * di;
        const int fb = sl * 8 + g * 4;     // feature base of this lane's float4
        const uint2 sv = *reinterpret_cast<const uint2*>(h1 + (size_t)n * DH + fb);
        float s0, s1, s2, s3;
        bf2x(sv.x, s0, s1); bf2x(sv.y, s2, s3);
        const float4 bv = *reinterpret_cast<const float4*>(b1 + fb);
        float4 o;
        o.x = fmaxf(acc[g * 4 + 0] + s0 * d2 + bv.x, 0.f);
        o.y = fmaxf(acc[g * 4 + 1] + s1 * d2 + bv.y, 0.f);
        o.z = fmaxf(acc[g * 4 + 2] + s2 * d2 + bv.z, 0.f);
        o.w = fmaxf(acc[g * 4 + 3] + s3 * d2 + bv.w, 0.f);
        *reinterpret_cast<float4*>(y1 + (size_t)n * DH + fb) = o;
    }
}

// ---------------------------------------------------------------------------
// Layer-2 aggregation from bf16 h2. One wave per node; 16 groups x 4 lanes
// (row = 32 bf16 = 64B = 4 x uint4) -> 16 rows in flight per load instr.
__global__ void k_agg2(const int* __restrict__ rowptr, const uint32_t* __restrict__ epack,
                       const uint16_t* __restrict__ h2, const float* __restrict__ dinv,
                       const float* __restrict__ b2, float* __restrict__ out) {
    const int gtid = blockIdx.x * blockDim.x + threadIdx.x;
    const int n    = gtid >> 6;
    const int lane = gtid & 63;
    if (n >= N) return;
    const int g  = lane >> 2;   // edge slot 0..15
    const int sl = lane & 3;    // features sl*8 .. sl*8+7
    const int beg = rowptr[n], end = rowptr[n + 1];

    float acc[8] = {0.f, 0.f, 0.f, 0.f, 0.f, 0.f, 0.f, 0.f};
    for (int j = beg; j < end; j += 16) {
        const int jj = j + g;
        int s = 0; float wn = 0.0f;
        if (jj < end) {
            const uint32_t w = epack[jj];
            s  = (int)(w & 0xFFFFu);
            wn = __half2float(__ushort_as_half((uint16_t)(w >> 16)));
        }
        const uint4 v = *reinterpret_cast<const uint4*>(h2 + (size_t)s * DO + sl * 8);
        float f0, f1;
        bf2x(v.x, f0, f1); acc[0] += wn * f0; acc[1] += wn * f1;
        bf2x(v.y, f0, f1); acc[2] += wn * f0; acc[3] += wn * f1;
        bf2x(v.z, f0, f1); acc[4] += wn * f0; acc[5] += wn * f1;
        bf2x(v.w, f0, f1); acc[6] += wn * f0; acc[7] += wn * f1;
    }
#pragma unroll
    for (int m = 4; m < 64; m <<= 1)    // sum over the 16 edge-groups
#pragma unroll
        for (int k = 0; k < 8; ++k) acc[k] += __shfl_xor(acc[k], m);

    if (g < 2) {   // 8 lanes x float4 = full 128B f32 out row
        const float di = dinv[n], d2 = di * di;
        const int fb = sl * 8 + g * 4;
        const uint2 sv = *reinterpret_cast<const uint2*>(h2 + (size_t)n * DO + fb);
        float s0, s1, s2, s3;
        bf2x(sv.x, s0, s1); bf2x(sv.y, s2, s3);
        const float4 bv = *reinterpret_cast<const float4*>(b2 + fb);
        float4 o;
        o.x = acc[g * 4 + 0] + s0 * d2 + bv.x;
        o.y = acc[g * 4 + 1] + s1 * d2 + bv.y;
        o.z = acc[g * 4 + 2] + s2 * d2 + bv.z;
        o.w = acc[g * 4 + 3] + s3 * d2 + bv.w;
        *reinterpret_cast<float4*>(out + (size_t)n * DO + fb) = o;
    }
}

// 64B-align each ws sub-buffer (16B vector loads require it)
template <typename T>
T* alignp(char*& p, size_t count) {
    uintptr_t u = ((uintptr_t)p + 63) & ~(uintptr_t)63;
    p = (char*)(u + count * sizeof(T));
    return (T*)u;
}

}  // namespace

extern "C" void kernel_launch(void* const* d_in, const int* in_sizes, int n_in,
                              void* d_out, int out_size, void* d_ws, size_t ws_size,
                              hipStream_t stream) {
    const float* x   = (const float*)d_in[0];
    const int*   ei  = (const int*)d_in[1];   // [2,E] int32: row0=src, row1=dst
    const float* W1  = (const float*)d_in[2];
    const float* b1  = (const float*)d_in[3];
    const float* W2  = (const float*)d_in[4];
    const float* b2  = (const float*)d_in[5];
    float* out = (float*)d_out;

    const int* src = ei;
    const int* dst = ei + E;

    // workspace layout, each 64B-aligned; total ~30 MB
    char* p = (char*)d_ws;
    int*      cnt    = alignp<int>(p, N);
    int*      rowptr = alignp<int>(p, N + 1);
    int*      rank   = alignp<int>(p, E);
    float*    dinv   = alignp<float>(p, N);
    int*      incl   = alignp<int>(p, N);
    int*      bsum   = alignp<int>(p, NB);
    uint32_t* epack  = alignp<uint32_t>(p, E);
    uint16_t* h1     = alignp<uint16_t>(p, (size_t)N * DH);   // bf16
    float*    y1     = alignp<float>(p, (size_t)N * DH);      // f32
    uint16_t* h2     = alignp<uint16_t>(p, (size_t)N * DO);   // bf16

    // 1. zero histogram
    hipLaunchKernelGGL(k_zero, dim3((N + 255) / 256), dim3(256), 0, stream, cnt);
    // 2. in-degree histogram + rank claim (1 edge/thread, high occupancy)
    hipLaunchKernelGGL(k_count, dim3((E + 255) / 256), dim3(256), 0, stream,
                       dst, cnt, rank);
    // 3. gemm1: h1 = x @ W1 (bf16, LDS-tiled)
    hipLaunchKernelGGL(k_gemm1, dim3((N + 63) / 64), dim3(256), 0, stream, x, W1, h1);
    // 4. scanA -> incl, bsum
    hipLaunchKernelGGL(k_scanA, dim3(NB), dim3(256), 0, stream, cnt, incl, bsum);
    // 5. scanBC (merged) -> rowptr, dinv
    hipLaunchKernelGGL(k_scanBC, dim3(NB), dim3(256), 0, stream,
                       cnt, incl, bsum, rowptr, dinv);
    // 6. CSR fill, atomic-free
    hipLaunchKernelGGL(k_fill, dim3((E + 255) / 256), dim3(256), 0, stream,
                       src, dst, rank, rowptr, dinv, epack);
    // 7. y1 = relu(aggregate(h1) + self + b1)   (one wave per node)
    hipLaunchKernelGGL(k_agg1, dim3((N * 64 + 255) / 256), dim3(256), 0, stream,
                       rowptr, epack, h1, dinv, b1, y1);
    // 8. gemm2: h2 = y1 @ W2 (bf16, LDS-tiled)
    hipLaunchKernelGGL(k_gemm2, dim3((N + 63) / 64), dim3(256), 0, stream, y1, W2, h2);
    // 9. out = aggregate(h2) + self + b2
    hipLaunchKernelGGL(k_agg2, dim3((N * 64 + 255) / 256), dim3(256), 0, stream,
                       rowptr, epack, h2, dinv, b2, out);
}

// Round 20
// 150.929 us; speedup vs baseline: 3.1767x; 1.0027x over previous
//
#include <hip/hip_runtime.h>
#include <hip/hip_fp16.h>
#include <cstddef>
#include <cstdint>

namespace {

constexpr int N  = 50000;   // nodes  (must fit u16 for edge packing)
constexpr int E  = 800000;  // edges
constexpr int DH = 64;      // hidden dim
constexpr int DO = 32;      // output dim
constexpr int NB = (N + 255) / 256;   // 196 scan blocks
static_assert(N < 65536, "src packed as u16");
static_assert(NB <= 256, "single-tile block scan");

__device__ inline uint16_t f2bf(float f) {   // RTNE
    union { float f; uint32_t u; } c; c.f = f;
    uint32_t r = c.u + 0x7FFFu + ((c.u >> 16) & 1u);
    return (uint16_t)(r >> 16);
}
// unpack packed pair of bf16 (low = first in memory)
__device__ inline void bf2x(uint32_t p, float& a, float& b) {
    union { uint32_t u; float f; } c0, c1;
    c0.u = p << 16; c1.u = p & 0xFFFF0000u;
    a = c0.f; b = c1.f;
}

// ---------------------------------------------------------------------------
__global__ void k_zero(int* __restrict__ cnt) {
    int i = blockIdx.x * blockDim.x + threadIdx.x;
    if (i < N) cnt[i] = 0;
}

// in-degree histogram + CSR rank claim. 1 edge/thread, tiny kernel ->
// high occupancy (lesson R14/R18: keep latency-bound atomics in their own
// minimal-VGPR kernel; merging with gemm either starves occupancy or spills).
__global__ void k_count(const int* __restrict__ dst, int* __restrict__ cnt,
                        int* __restrict__ rank) {
    int e = blockIdx.x * blockDim.x + threadIdx.x;
    if (e < E) rank[e] = atomicAdd(&cnt[dst[e]], 1);
}

// ---------------------------------------------------------------------------
// scanA: per-block (256-wide) inclusive scan of cnt -> incl, block total -> bsum
__global__ void k_scanA(const int* __restrict__ cnt, int* __restrict__ incl,
                        int* __restrict__ bsum) {
    __shared__ int ts[256];
    const int t = threadIdx.x;
    const int i = blockIdx.x * 256 + t;
    const int v = (i < N) ? cnt[i] : 0;
    ts[t] = v;
    __syncthreads();
#pragma unroll
    for (int off = 1; off < 256; off <<= 1) {
        const int u = (t >= off) ? ts[t - off] : 0;
        __syncthreads();
        ts[t] += u;
        __syncthreads();
    }
    if (i < N) incl[i] = ts[t];
    if (t == 255) bsum[blockIdx.x] = ts[255];
}

// scanBC (merged): each block redundantly scans the 196-entry bsum in LDS,
// takes its own exclusive base, emits rowptr/dinv.
__global__ void k_scanBC(const int* __restrict__ cnt, const int* __restrict__ incl,
                         const int* __restrict__ bsum, int* __restrict__ rowptr,
                         float* __restrict__ dinv) {
    __shared__ int ts[256];
    const int t = threadIdx.x;
    ts[t] = (t < NB) ? bsum[t] : 0;
    __syncthreads();
#pragma unroll
    for (int off = 1; off < 256; off <<= 1) {
        const int u = (t >= off) ? ts[t - off] : 0;
        __syncthreads();
        ts[t] += u;
        __syncthreads();
    }
    const int base = (blockIdx.x == 0) ? 0 : ts[blockIdx.x - 1];
    const int i = blockIdx.x * 256 + t;
    if (i >= N) return;
    const int c    = cnt[i];
    const int excl = base + incl[i] - c;
    rowptr[i] = excl;
    dinv[i]   = rsqrtf((float)(c + 1));
    if (i == N - 1) rowptr[N] = excl + c;   // == E
}

// CSR fill, atomic-free: pos = rowptr[dst] + rank (unique by construction).
// Standalone (lesson R18: merging with gemm1 spilled gemm accumulators).
__global__ void k_fill(const int* __restrict__ src, const int* __restrict__ dst,
                       const int* __restrict__ rank, const int* __restrict__ rowptr,
                       const float* __restrict__ dinv, uint32_t* __restrict__ epack) {
    int e = blockIdx.x * blockDim.x + threadIdx.x;
    if (e >= E) return;
    const int s = src[e], d = dst[e];
    const int pos = rowptr[d] + rank[e];
    const float wn = dinv[s] * dinv[d];
    const uint16_t hb = __half_as_ushort(__float2half(wn));
    epack[pos] = (uint32_t)s | ((uint32_t)hb << 16);
}

// ---------------------------------------------------------------------------
// gemm1: h1[N,64] = X[N,64] @ W1[64,64] -> bf16. LDS-tiled, X read once.
__launch_bounds__(256)
__global__ void k_gemm1(const float* __restrict__ X, const float* __restrict__ W1,
                        uint16_t* __restrict__ h1) {
    __shared__ float Ws[64 * DH];   // 16 KB
    __shared__ float Xs[64 * 68];   // 17.4 KB (padded stride 68)

    const int tid = threadIdx.x;
    const int rowBase = blockIdx.x * 64;

#pragma unroll
    for (int i = 0; i < 4; ++i) {   // stage W1: 1024 f4, coalesced
        const int q = tid + i * 256;
        reinterpret_cast<float4*>(Ws)[q] = reinterpret_cast<const float4*>(W1)[q];
    }
#pragma unroll
    for (int i = 0; i < 4; ++i) {   // stage X tile, coalesced; clamp tail rows
        const int q   = tid + i * 256;
        const int row = q >> 4;
        const int kq  = q & 15;
        const int gr  = min(rowBase + row, N - 1);
        const float4 v = *reinterpret_cast<const float4*>(X + (size_t)gr * 64 + kq * 4);
        *reinterpret_cast<float4*>(&Xs[row * 68 + kq * 4]) = v;
    }
    __syncthreads();

    const int rg = tid >> 4;        // row group (4 rows)
    const int cg = tid & 15;        // col group (4 cols)
    float acc[4][4];
#pragma unroll
    for (int r = 0; r < 4; ++r)
#pragma unroll
        for (int c = 0; c < 4; ++c) acc[r][c] = 0.0f;

#pragma unroll
    for (int k4 = 0; k4 < 16; ++k4) {
        const int k = k4 * 4;
        float xr[4][4];
#pragma unroll
        for (int r = 0; r < 4; ++r) {
            const float4 v = *reinterpret_cast<const float4*>(&Xs[(rg * 4 + r) * 68 + k]);
            xr[r][0] = v.x; xr[r][1] = v.y; xr[r][2] = v.z; xr[r][3] = v.w;
        }
#pragma unroll
        for (int i = 0; i < 4; ++i) {
            const float4 v = *reinterpret_cast<const float4*>(&Ws[(k + i) * DH + cg * 4]);
            const float wv[4] = {v.x, v.y, v.z, v.w};
#pragma unroll
            for (int r = 0; r < 4; ++r)
#pragma unroll
                for (int c = 0; c < 4; ++c) acc[r][c] += xr[r][i] * wv[c];
        }
    }

#pragma unroll
    for (int r = 0; r < 4; ++r) {
        const int row = rowBase + rg * 4 + r;
        if (row < N) {
            uint2 o;
            o.x = (uint32_t)f2bf(acc[r][0]) | ((uint32_t)f2bf(acc[r][1]) << 16);
            o.y = (uint32_t)f2bf(acc[r][2]) | ((uint32_t)f2bf(acc[r][3]) << 16);
            *reinterpret_cast<uint2*>(&h1[(size_t)row * DH + cg * 4]) = o;
        }
    }
}

// ---------------------------------------------------------------------------
// gemm2: h2[N,32] = y1[N,64](bf16) @ W2[64,32] -> bf16. LDS-tiled; y1
// converted bf16->f32 during staging, compute loop identical to R19.
__launch_bounds__(256)
__global__ void k_gemm2(const uint16_t* __restrict__ Y, const float* __restrict__ W2,
                        uint16_t* __restrict__ h2) {
    __shared__ float Ws[64 * DO];   // 8 KB
    __shared__ float Xs[64 * 68];   // 17.4 KB

    const int tid = threadIdx.x;
    const int rowBase = blockIdx.x * 64;

#pragma unroll
    for (int i = 0; i < 2; ++i) {   // stage W2: 512 f4
        const int q = tid + i * 256;
        reinterpret_cast<float4*>(Ws)[q] = reinterpret_cast<const float4*>(W2)[q];
    }
#pragma unroll
    for (int i = 0; i < 2; ++i) {   // stage y1 tile: 64 rows x 128B = 512 uint4
        const int q    = tid + i * 256;
        const int row  = q >> 3;          // 8 uint4 per row
        const int slot = q & 7;           // 8 bf16 per uint4
        const int gr   = min(rowBase + row, N - 1);
        const uint4 v = *reinterpret_cast<const uint4*>(Y + (size_t)gr * DH + slot * 8);
        float f0, f1;
        float4 a, b;
        bf2x(v.x, f0, f1); a.x = f0; a.y = f1;
        bf2x(v.y, f0, f1); a.z = f0; a.w = f1;
        bf2x(v.z, f0, f1); b.x = f0; b.y = f1;
        bf2x(v.w, f0, f1); b.z = f0; b.w = f1;
        *reinterpret_cast<float4*>(&Xs[row * 68 + slot * 8])     = a;
        *reinterpret_cast<float4*>(&Xs[row * 68 + slot * 8 + 4]) = b;
    }
    __syncthreads();

    const int rg = tid >> 4;        // row group (4 rows)
    const int cg = tid & 15;        // col group (2 cols)
    float acc[4][2];
#pragma unroll
    for (int r = 0; r < 4; ++r) { acc[r][0] = 0.0f; acc[r][1] = 0.0f; }

#pragma unroll
    for (int k4 = 0; k4 < 16; ++k4) {
        const int k = k4 * 4;
        float xr[4][4];
#pragma unroll
        for (int r = 0; r < 4; ++r) {
            const float4 v = *reinterpret_cast<const float4*>(&Xs[(rg * 4 + r) * 68 + k]);
            xr[r][0] = v.x; xr[r][1] = v.y; xr[r][2] = v.z; xr[r][3] = v.w;
        }
#pragma unroll
        for (int i = 0; i < 4; ++i) {
            const float2 v = *reinterpret_cast<const float2*>(&Ws[(k + i) * DO + cg * 2]);
#pragma unroll
            for (int r = 0; r < 4; ++r) {
                acc[r][0] += xr[r][i] * v.x;
                acc[r][1] += xr[r][i] * v.y;
            }
        }
    }

#pragma unroll
    for (int r = 0; r < 4; ++r) {
        const int row = rowBase + rg * 4 + r;
        if (row < N) {
            const uint32_t o = (uint32_t)f2bf(acc[r][0]) | ((uint32_t)f2bf(acc[r][1]) << 16);
            *reinterpret_cast<uint32_t*>(&h2[(size_t)row * DO + cg * 2]) = o;
        }
    }
}

// ---------------------------------------------------------------------------
// Layer-1 aggregation, unfused (lesson R16). One wave per node;
// 8 groups(g) x 8 lanes(sl); y1 bf16 out (this round's lever).
__launch_bounds__(256)
__global__ void k_agg1(const int* __restrict__ rowptr, const uint32_t* __restrict__ epack,
                       const uint16_t* __restrict__ h1, const float* __restrict__ dinv,
                       const float* __restrict__ b1, uint16_t* __restrict__ y1) {
    const int gtid = blockIdx.x * 256 + threadIdx.x;
    const int n    = gtid >> 6;
    const int lane = threadIdx.x & 63;
    if (n >= N) return;
    const int g  = lane >> 3;   // edge slot 0..7
    const int sl = lane & 7;    // 16B feature slice
    const int beg = rowptr[n], end = rowptr[n + 1];

    float acc[8] = {0.f, 0.f, 0.f, 0.f, 0.f, 0.f, 0.f, 0.f};
    for (int j = beg; j < end; j += 8) {
        const int jj = j + g;
        int s = 0; float wn = 0.0f;
        if (jj < end) {
            const uint32_t w = epack[jj];
            s  = (int)(w & 0xFFFFu);
            wn = __half2float(__ushort_as_half((uint16_t)(w >> 16)));
        }
        const uint4 v = *reinterpret_cast<const uint4*>(h1 + (size_t)s * DH + sl * 8);
        float f0, f1;
        bf2x(v.x, f0, f1); acc[0] += wn * f0; acc[1] += wn * f1;
        bf2x(v.y, f0, f1); acc[2] += wn * f0; acc[3] += wn * f1;
        bf2x(v.z, f0, f1); acc[4] += wn * f0; acc[5] += wn * f1;
        bf2x(v.w, f0, f1); acc[6] += wn * f0; acc[7] += wn * f1;
    }
#pragma unroll
    for (int m = 8; m < 64; m <<= 1)        // sum over the 8 edge-groups
#pragma unroll
        for (int k = 0; k < 8; ++k) acc[k] += __shfl_xor(acc[k], m);

    if (g < 2) {   // 16 lanes write 8B each = full 128B bf16 y1 row
        const float di = dinv[n], d2 = di * di;
        const int fb = sl * 8 + g * 4;     // feature base of this lane's quad
        const uint2 sv = *reinterpret_cast<const uint2*>(h1 + (size_t)n * DH + fb);
        float s0, s1, s2, s3;
        bf2x(sv.x, s0, s1); bf2x(sv.y, s2, s3);
        const float4 bv = *reinterpret_cast<const float4*>(b1 + fb);
        const float o0 = fmaxf(acc[g * 4 + 0] + s0 * d2 + bv.x, 0.f);
        const float o1 = fmaxf(acc[g * 4 + 1] + s1 * d2 + bv.y, 0.f);
        const float o2 = fmaxf(acc[g * 4 + 2] + s2 * d2 + bv.z, 0.f);
        const float o3 = fmaxf(acc[g * 4 + 3] + s3 * d2 + bv.w, 0.f);
        uint2 pk;
        pk.x = (uint32_t)f2bf(o0) | ((uint32_t)f2bf(o1) << 16);
        pk.y = (uint32_t)f2bf(o2) | ((uint32_t)f2bf(o3) << 16);
        *reinterpret_cast<uint2*>(y1 + (size_t)n * DH + fb) = pk;
    }
}

// ---------------------------------------------------------------------------
// Layer-2 aggregation from bf16 h2. One wave per node; 16 groups x 4 lanes
// (row = 32 bf16 = 64B = 4 x uint4) -> 16 rows in flight per load instr.
__global__ void k_agg2(const int* __restrict__ rowptr, const uint32_t* __restrict__ epack,
                       const uint16_t* __restrict__ h2, const float* __restrict__ dinv,
                       const float* __restrict__ b2, float* __restrict__ out) {
    const int gtid = blockIdx.x * blockDim.x + threadIdx.x;
    const int n    = gtid >> 6;
    const int lane = gtid & 63;
    if (n >= N) return;
    const int g  = lane >> 2;   // edge slot 0..15
    const int sl = lane & 3;    // features sl*8 .. sl*8+7
    const int beg = rowptr[n], end = rowptr[n + 1];

    float acc[8] = {0.f, 0.f, 0.f, 0.f, 0.f, 0.f, 0.f, 0.f};
    for (int j = beg; j < end; j += 16) {
        const int jj = j + g;
        int s = 0; float wn = 0.0f;
        if (jj < end) {
            const uint32_t w = epack[jj];
            s  = (int)(w & 0xFFFFu);
            wn = __half2float(__ushort_as_half((uint16_t)(w >> 16)));
        }
        const uint4 v = *reinterpret_cast<const uint4*>(h2 + (size_t)s * DO + sl * 8);
        float f0, f1;
        bf2x(v.x, f0, f1); acc[0] += wn * f0; acc[1] += wn * f1;
        bf2x(v.y, f0, f1); acc[2] += wn * f0; acc[3] += wn * f1;
        bf2x(v.z, f0, f1); acc[4] += wn * f0; acc[5] += wn * f1;
        bf2x(v.w, f0, f1); acc[6] += wn * f0; acc[7] += wn * f1;
    }
#pragma unroll
    for (int m = 4; m < 64; m <<= 1)    // sum over the 16 edge-groups
#pragma unroll
        for (int k = 0; k < 8; ++k) acc[k] += __shfl_xor(acc[k], m);

    if (g < 2) {   // 8 lanes x float4 = full 128B f32 out row
        const float di = dinv[n], d2 = di * di;
        const int fb = sl * 8 + g * 4;
        const uint2 sv = *reinterpret_cast<const uint2*>(h2 + (size_t)n * DO + fb);
        float s0, s1, s2, s3;
        bf2x(sv.x, s0, s1); bf2x(sv.y, s2, s3);
        const float4 bv = *reinterpret_cast<const float4*>(b2 + fb);
        float4 o;
        o.x = acc[g * 4 + 0] + s0 * d2 + bv.x;
        o.y = acc[g * 4 + 1] + s1 * d2 + bv.y;
        o.z = acc[g * 4 + 2] + s2 * d2 + bv.z;
        o.w = acc[g * 4 + 3] + s3 * d2 + bv.w;
        *reinterpret_cast<float4*>(out + (size_t)n * DO + fb) = o;
    }
}

// 64B-align each ws sub-buffer (16B vector loads require it)
template <typename T>
T* alignp(char*& p, size_t count) {
    uintptr_t u = ((uintptr_t)p + 63) & ~(uintptr_t)63;
    p = (char*)(u + count * sizeof(T));
    return (T*)u;
}

}  // namespace

extern "C" void kernel_launch(void* const* d_in, const int* in_sizes, int n_in,
                              void* d_out, int out_size, void* d_ws, size_t ws_size,
                              hipStream_t stream) {
    const float* x   = (const float*)d_in[0];
    const int*   ei  = (const int*)d_in[1];   // [2,E] int32: row0=src, row1=dst
    const float* W1  = (const float*)d_in[2];
    const float* b1  = (const float*)d_in[3];
    const float* W2  = (const float*)d_in[4];
    const float* b2  = (const float*)d_in[5];
    float* out = (float*)d_out;

    const int* src = ei;
    const int* dst = ei + E;

    // workspace layout, each 64B-aligned; total ~24 MB
    char* p = (char*)d_ws;
    int*      cnt    = alignp<int>(p, N);
    int*      rowptr = alignp<int>(p, N + 1);
    int*      rank   = alignp<int>(p, E);
    float*    dinv   = alignp<float>(p, N);
    int*      incl   = alignp<int>(p, N);
    int*      bsum   = alignp<int>(p, NB);
    uint32_t* epack  = alignp<uint32_t>(p, E);
    uint16_t* h1     = alignp<uint16_t>(p, (size_t)N * DH);   // bf16
    uint16_t* y1     = alignp<uint16_t>(p, (size_t)N * DH);   // bf16 (this round)
    uint16_t* h2     = alignp<uint16_t>(p, (size_t)N * DO);   // bf16

    // 1. zero histogram
    hipLaunchKernelGGL(k_zero, dim3((N + 255) / 256), dim3(256), 0, stream, cnt);
    // 2. in-degree histogram + rank claim (1 edge/thread, high occupancy)
    hipLaunchKernelGGL(k_count, dim3((E + 255) / 256), dim3(256), 0, stream,
                       dst, cnt, rank);
    // 3. gemm1: h1 = x @ W1 (bf16, LDS-tiled)
    hipLaunchKernelGGL(k_gemm1, dim3((N + 63) / 64), dim3(256), 0, stream, x, W1, h1);
    // 4. scanA -> incl, bsum
    hipLaunchKernelGGL(k_scanA, dim3(NB), dim3(256), 0, stream, cnt, incl, bsum);
    // 5. scanBC (merged) -> rowptr, dinv
    hipLaunchKernelGGL(k_scanBC, dim3(NB), dim3(256), 0, stream,
                       cnt, incl, bsum, rowptr, dinv);
    // 6. CSR fill, atomic-free
    hipLaunchKernelGGL(k_fill, dim3((E + 255) / 256), dim3(256), 0, stream,
                       src, dst, rank, rowptr, dinv, epack);
    // 7. y1 = relu(aggregate(h1) + self + b1) -> bf16 (one wave per node)
    hipLaunchKernelGGL(k_agg1, dim3((N * 64 + 255) / 256), dim3(256), 0, stream,
                       rowptr, epack, h1, dinv, b1, y1);
    // 8. gemm2: h2 = y1 @ W2 (bf16 in/out, LDS-tiled)
    hipLaunchKernelGGL(k_gemm2, dim3((N + 63) / 64), dim3(256), 0, stream, y1, W2, h2);
    // 9. out = aggregate(h2) + self + b2
    hipLaunchKernelGGL(k_agg2, dim3((N * 64 + 255) / 256), dim3(256), 0, stream,
                       rowptr, epack, h2, dinv, b2, out);
}